// Round 9
// baseline (374.832 us; speedup 1.0000x reference)
//
#include <hip/hip_runtime.h>
#include <cmath>

#define Bz 4
#define Tz 1000
#define Wz 32
#define Dz 200
#define EDz 400
#define Nz 16
#define DTRz 13
#define Lz 1001
#define POSz 500
#define LPz 501
#define TSTR 512
#define ESP 10      // e-splits in k_mid (40 e each)
#define NEG_BIG -1e30f

__device__ __forceinline__ float wave_sum(float v) {
#pragma unroll
  for (int o = 32; o; o >>= 1) v += __shfl_xor(v, o);
  return v;
}

// grid = 9 + 1000 blocks.
// blocks 0..8: setup (v[e], CLS row -> xn[POS], z) + counter zeroing.
// blocks 9..1008: word-pool, ONE WAVE PER TWEET (4 tweets/block).
__global__ __launch_bounds__(256) void k_front(
    const float* __restrict__ x, const int* __restrict__ n_tweets,
    const int* __restrict__ n_words, const float* __restrict__ w_attn,
    const float* __restrict__ b_attn, const float* __restrict__ norm_w,
    const float* __restrict__ cls, const float* __restrict__ out_proj,
    const float* __restrict__ head_w, const float* __restrict__ ipf,
    const float* __restrict__ ipb, float* __restrict__ xn,
    float* __restrict__ zbuf, float* __restrict__ vbuf,
    int* __restrict__ cnts) {
  int bid = blockIdx.x;
  int tid = threadIdx.x;
  int wave = tid >> 6, lane = tid & 63;
  if (bid < 9) {
    if (bid == 0) {
      if (tid < 72) cnts[tid] = 0;   // 64 mid-group counters + 1 scan counter
      __shared__ float hw[Dz];
      if (tid < Dz) hw[tid] = head_w[tid];
      __syncthreads();
      for (int e = tid; e < EDz; e += 256) {
        float acc = 0.f;
        for (int d = 0; d < Dz; d += 4) {
          float4 ov = *(const float4*)(out_proj + e * Dz + d);
          acc += ov.x * hw[d] + ov.y * hw[d + 1] + ov.z * hw[d + 2] + ov.w * hw[d + 3];
        }
        vbuf[e] = acc;
      }
      return;
    }
    int id = bid - 1;
    int br = id >> 2, b = id & 3;
    __shared__ float xs[Dz];
    __shared__ float s_red[4];
    float val = (tid < Dz) ? cls[tid] : 0.f;
    float sq = wave_sum(val * val);
    if ((tid & 63) == 0) s_red[tid >> 6] = sq;
    __syncthreads();
    float tot = s_red[0] + s_red[1] + s_red[2] + s_red[3];
    float scale = rsqrtf(tot * (1.f / Dz) + 1e-5f);
    if (tid < Dz) {
      float o = val * scale * norm_w[tid];
      xs[tid] = o;
      if (br == 0) xn[((size_t)b * Lz + POSz) * Dz + tid] = o;
    }
    __syncthreads();
    const float* ip = br ? ipb : ipf;
    for (int e = tid; e < EDz; e += 256) {
      float acc = 0.f;
      for (int d = 0; d < Dz; ++d) acc += xs[d] * ip[d * (2 * EDz) + EDz + e];
      zbuf[((size_t)br * Bz + b) * EDz + e] = acc;
    }
    return;
  }
  // ---- pool: one wave per (b,t) ----
  int bt = (bid - 9) * 4 + wave;          // 0..3999
  int b = bt / Tz, t = bt - b * Tz;
  int l = (t < POSz) ? t : t + 1;
  float* outr = xn + ((size_t)b * Lz + l) * Dz;
  int ntw = n_tweets[b]; if (ntw > Tz) ntw = Tz;
  if (t >= ntw) {
    if (lane < 50) *(float4*)(outr + lane * 4) = make_float4(0.f, 0.f, 0.f, 0.f);
    return;
  }
  int nw = n_words[b * Tz + t]; if (nw > Wz) nw = Wz; if (nw < 1) nw = 1;
  const float* xs = x + ((size_t)(b * Tz + t)) * (Wz * Dz);
  int h = lane & 1, w = lane >> 1;
  float sc = 0.f;
  if (w < nw) {
    const float* xr = xs + w * Dz + h * 100;
    const float* wr = w_attn + h * 100;
#pragma unroll
    for (int i = 0; i < 25; ++i) {
      float4 xv = *(const float4*)(xr + i * 4);
      float4 wv = *(const float4*)(wr + i * 4);
      sc += xv.x * wv.x + xv.y * wv.y + xv.z * wv.z + xv.w * wv.w;
    }
  }
  sc += __shfl_xor(sc, 1);
  float scv = (w < nw) ? (sc + b_attn[0]) : NEG_BIG;
  float m = scv;
#pragma unroll
  for (int o = 32; o; o >>= 1) m = fmaxf(m, __shfl_xor(m, o));
  float en = __expf(scv - m);
  float es = (h == 0) ? en : 0.f;
  float tot = wave_sum(es);
  en /= tot;
  float4 val = make_float4(0.f, 0.f, 0.f, 0.f);
  const float* xc = xs + lane * 4;
  for (int ww = 0; ww < nw; ++ww) {
    float aw = __shfl(en, 2 * ww);
    if (lane < 50) {
      float4 xv = *(const float4*)(xc + ww * Dz);
      val.x += aw * xv.x; val.y += aw * xv.y;
      val.z += aw * xv.z; val.w += aw * xv.w;
    }
  }
  float sq = (lane < 50) ? (val.x * val.x + val.y * val.y + val.z * val.z + val.w * val.w) : 0.f;
  sq = wave_sum(sq);
  float scale = rsqrtf(sq * (1.f / Dz) + 1e-5f);
  if (lane < 50) {
    float4 nw4 = *(const float4*)(norm_w + lane * 4);
    float4 o = make_float4(val.x * scale * nw4.x, val.y * scale * nw4.y,
                           val.z * scale * nw4.z, val.w * scale * nw4.w);
    *(float4*)(outr + lane * 4) = o;
  }
}

// Register-tiled GEMM: P^T[brb][e][t] = sum_d W[d][e] * X[t][d].
__global__ __launch_bounds__(256) void k_gemm(
    const float* __restrict__ xn, const float* __restrict__ ipf,
    const float* __restrict__ ipb, float* __restrict__ P) {
  int bid = blockIdx.x;
  int brb = bid / 56;
  int rr = bid - brb * 56;
  int tt = rr / 7, ee = rr - tt * 7;
  int br = brb >> 2, b = brb & 3;
  int t0 = tt * 64, e0 = ee * 64;
  const float* ip = br ? ipb : ipf;
  int tid = threadIdx.x;
  int tx = tid & 15, ty = tid >> 4;

  __shared__ float Xs[16][64 + 4];
  __shared__ float Ws[16][64 + 4];

  float acc[4][4];
#pragma unroll
  for (int i = 0; i < 4; ++i)
#pragma unroll
    for (int j = 0; j < 4; ++j) acc[i][j] = 0.f;

  int xr = tid >> 2, xc = (tid & 3) * 4;
  int wr = tid >> 4, wc = (tid & 15) * 4;
  int t = t0 + xr;
  bool tok = (t < LPz);
  int l = br ? (Lz - 1 - t) : t;
  const float* xrow = xn + ((size_t)b * Lz + l) * Dz;

  for (int dk = 0; dk < 200; dk += 16) {
    float xv[4], wv[4];
#pragma unroll
    for (int c = 0; c < 4; ++c) {
      int d = dk + xc + c;
      xv[c] = (tok && d < Dz) ? xrow[d] : 0.f;
    }
    int dw = dk + wr;
#pragma unroll
    for (int c = 0; c < 4; ++c) {
      int e = e0 + wc + c;
      wv[c] = (dw < Dz && e < EDz) ? ip[(size_t)dw * (2 * EDz) + e] : 0.f;
    }
    __syncthreads();
#pragma unroll
    for (int c = 0; c < 4; ++c) Xs[xc + c][xr] = xv[c];
#pragma unroll
    for (int c = 0; c < 4; ++c) Ws[wr][wc + c] = wv[c];
    __syncthreads();
#pragma unroll
    for (int k = 0; k < 16; ++k) {
      float4 a4 = *(const float4*)&Xs[k][ty * 4];
      float4 b4 = *(const float4*)&Ws[k][tx * 4];
      float av[4] = {a4.x, a4.y, a4.z, a4.w};
      float bv[4] = {b4.x, b4.y, b4.z, b4.w};
#pragma unroll
      for (int i = 0; i < 4; ++i)
#pragma unroll
        for (int j = 0; j < 4; ++j) acc[i][j] += av[i] * bv[j];
    }
  }
#pragma unroll
  for (int j = 0; j < 4; ++j) {
    int e = e0 + tx * 4 + j;
    if (e < EDz) {
      float4 o = make_float4(acc[0][j], acc[1][j], acc[2][j], acc[3][j]);
      *(float4*)&P[((size_t)brb * EDz + e) * TSTR + t0 + ty * 4] = o;
    }
  }
}

// conv+silu -> xp_t ; xproj partials -> dbcp ; LAST block of each (brb,tc)
// group sums the 10 partials and computes dt_t / Bm_t / Cend (replaces k_dt2).
__global__ __launch_bounds__(256) void k_mid2(
    const float* __restrict__ P,
    const float* __restrict__ cwf, const float* __restrict__ cwb,
    const float* __restrict__ cbf, const float* __restrict__ cbb,
    const float* __restrict__ xpjf, const float* __restrict__ xpjb,
    const float* __restrict__ dtwf, const float* __restrict__ dtwb,
    const float* __restrict__ dtbf, const float* __restrict__ dtbb,
    float* __restrict__ xp_t, float* __restrict__ dbcp,
    float* __restrict__ dt_t, float* __restrict__ Bm_t,
    float* __restrict__ Cend, int* __restrict__ cnts) {
  int bid = blockIdx.x;
  int esp = bid % ESP;
  int rem = bid / ESP;
  int tc = rem & 7, brb = rem >> 3;
  int br = brb >> 2;
  int tid = threadIdx.x;
  int wave = tid >> 6, lane = tid & 63;
  int t = tc * 64 + lane;
  const float* cw = br ? cwb : cwf;
  const float* cb = br ? cbb : cbf;
  const float* xpj = br ? xpjb : xpjf;

  __shared__ float sred[4][64][45];
  __shared__ float dfin[DTRz * 64];
  __shared__ int s_last;

  float accq[45];
#pragma unroll
  for (int q = 0; q < 45; ++q) accq[q] = 0.f;

  const float* Pb = P + (size_t)brb * EDz * TSTR;
  int e0 = esp * 40 + wave * 10;
#pragma unroll 2
  for (int i = 0; i < 10; ++i) {
    int e = e0 + i;
    const float* pr = Pb + (size_t)e * TSTR;
    float p0 = (t >= 3) ? pr[t - 3] : 0.f;
    float p1 = (t >= 2) ? pr[t - 2] : 0.f;
    float p2 = (t >= 1) ? pr[t - 1] : 0.f;
    float p3 = pr[t];
    float4 c4 = *(const float4*)(cw + e * 4);
    float a = cb[e] + c4.x * p0 + c4.y * p1 + c4.z * p2 + c4.w * p3;
    float sp = a / (1.f + __expf(-a));
    xp_t[((size_t)brb * EDz + e) * TSTR + t] = sp;
    const float* xq = xpj + e * 45;
#pragma unroll
    for (int q = 0; q < 45; ++q) accq[q] += sp * xq[q];
  }
#pragma unroll
  for (int q = 0; q < 45; ++q) sred[wave][lane][q] = accq[q];
  __syncthreads();
  if (wave < 2) {
#pragma unroll
    for (int q = 0; q < 45; ++q)
      sred[wave][lane][q] += sred[wave + 2][lane][q];
  }
  __syncthreads();
  if (wave == 0) {
    float* dp = dbcp + ((size_t)(esp * 8 + brb) * 45) * TSTR + t;
#pragma unroll
    for (int q = 0; q < 45; ++q)
      dp[(size_t)q * TSTR] = sred[0][lane][q] + sred[1][lane][q];
  }
  // ---- last-block-done handoff ----
  __syncthreads();
  __threadfence();
  if (tid == 0) {
    int old = atomicAdd(&cnts[brb * 8 + tc], 1);
    s_last = (old == ESP - 1) ? 1 : 0;
  }
  __syncthreads();
  if (!s_last) return;
  __threadfence();

  const size_t espstr = (size_t)8 * 45 * TSTR;
  // dfin[q][tl] = sum of 10 partials (q<13)
  for (int idx = tid; idx < DTRz * 64; idx += 256) {
    int q = idx >> 6, tl = idx & 63;
    size_t base = ((size_t)brb * 45 + q) * TSTR + tc * 64 + tl;
    float s = 0.f;
#pragma unroll
    for (int e2 = 0; e2 < ESP; ++e2) s += dbcp[base + e2 * espstr];
    dfin[q * 64 + tl] = s;
  }
  // Bm_t
  for (int idx = tid; idx < Nz * 64; idx += 256) {
    int n = idx >> 6, tl = idx & 63;
    size_t base = ((size_t)brb * 45 + 13 + n) * TSTR + tc * 64 + tl;
    float s = 0.f;
#pragma unroll
    for (int e2 = 0; e2 < ESP; ++e2) s += dbcp[base + e2 * espstr];
    Bm_t[((size_t)brb * Nz + n) * TSTR + tc * 64 + tl] = s;
  }
  // Cend (t == POSz lives in tc == 7)
  if (tc == 7 && tid < Nz) {
    size_t base = ((size_t)brb * 45 + 29 + tid) * TSTR + POSz;
    float s = 0.f;
#pragma unroll
    for (int e2 = 0; e2 < ESP; ++e2) s += dbcp[base + e2 * espstr];
    Cend[brb * Nz + tid] = s;
  }
  __syncthreads();
  const float* dtw = br ? dtwb : dtwf;
  const float* dtb = br ? dtbb : dtbf;
  float dq[DTRz];
#pragma unroll
  for (int q = 0; q < DTRz; ++q) dq[q] = dfin[q * 64 + lane];
  int ew0 = wave * 100;
#pragma unroll 2
  for (int i = 0; i < 100; ++i) {
    int e = ew0 + i;
    float s = dtb[e];
#pragma unroll
    for (int q = 0; q < DTRz; ++q) s += dq[q] * dtw[q * EDz + e];
    float dtv = (s > 20.f) ? s : log1pf(__expf(s));
    dt_t[((size_t)brb * EDz + e) * TSTR + t] = dtv;
  }
}

// Scan; LAST of the 3200 blocks does the final fixed-order reduce + sigmoid.
__global__ __launch_bounds__(64) void k_scan2(
    const float* __restrict__ xp_t, const float* __restrict__ dt_t,
    const float* __restrict__ Bm_t, const float* __restrict__ Cend,
    const float* __restrict__ Alogf, const float* __restrict__ Alogb,
    const float* __restrict__ Dpf, const float* __restrict__ Dpb,
    const float* __restrict__ zbuf, const float* __restrict__ vbuf,
    float* __restrict__ ybuf, const float* __restrict__ cls,
    const float* __restrict__ head_w, const float* __restrict__ head_b,
    float* __restrict__ out, int* __restrict__ cnt) {
  int blk = blockIdx.x;
  int br = blk / (Bz * EDz);
  int rem = blk - br * (Bz * EDz);
  int b = rem / EDz, e = rem - b * EDz;
  int lane = threadIdx.x;
  const float* A_log = br ? Alogb : Alogf;
  const float* Dp = br ? Dpb : Dpf;
  float A[Nz];
  {
    const float4* ap = (const float4*)(A_log + e * Nz);
#pragma unroll
    for (int q = 0; q < 4; ++q) {
      float4 a4 = ap[q];
      A[q * 4 + 0] = -__expf(a4.x); A[q * 4 + 1] = -__expf(a4.y);
      A[q * 4 + 2] = -__expf(a4.z); A[q * 4 + 3] = -__expf(a4.w);
    }
  }
  size_t base = ((size_t)(br * Bz + b) * EDz + e) * TSTR;
  const float* dtp = dt_t + base;
  const float* xpp = xp_t + base;
  const float* bmp = Bm_t + (size_t)(br * Bz + b) * Nz * TSTR;
  float loc = 0.f;
#pragma unroll
  for (int c = 0; c < 8; ++c) {
    int t = c * 64 + lane;
    if (t < LPz) loc += dtp[t];
  }
  float Stot = wave_sum(loc);
  float acc[Nz];
#pragma unroll
  for (int n = 0; n < Nz; ++n) acc[n] = 0.f;
  float carry = 0.f;
  for (int c = 0; c < 8; ++c) {
    int t = c * 64 + lane;
    bool act = t < LPz;
    float dtt = 0.f, xv = 0.f;
    if (act) { dtt = dtp[t]; xv = xpp[t]; }
    float s = dtt;
#pragma unroll
    for (int o = 1; o < 64; o <<= 1) {
      float u = __shfl_up(s, o);
      s += (lane >= o) ? u : 0.f;
    }
    float S = carry + s;
    carry += __shfl(s, 63);
    float wt = dtt * xv;
    float decay = Stot - S;  // >= 0, A<0 => exp<=1
#pragma unroll
    for (int n = 0; n < Nz; ++n) {
      float bv = 0.f;
      if (act) bv = bmp[n * TSTR + t];
      acc[n] += __expf(A[n] * decay) * wt * bv;
    }
  }
#pragma unroll
  for (int o = 32; o; o >>= 1) {
#pragma unroll
    for (int n = 0; n < Nz; ++n) acc[n] += __shfl_xor(acc[n], o);
  }
  if (lane == 0) {
    float y = Dp[e] * xpp[LPz - 1];
#pragma unroll
    for (int n = 0; n < Nz; ++n) y += Cend[(br * Bz + b) * Nz + n] * acc[n];
    float zz = zbuf[((size_t)br * Bz + b) * EDz + e];
    float sz = zz / (1.f + __expf(-zz));
    ybuf[((size_t)br * Bz + b) * EDz + e] = y * sz * vbuf[e];
  }
  // ---- last-block-done final ----
  __threadfence();
  int old = 0;
  if (lane == 0) old = atomicAdd(cnt, 1);
  old = __shfl(old, 0);
  if (old != 2 * Bz * EDz - 1) return;
  __threadfence();
  float ch = 0.f;
  for (int d = lane; d < Dz; d += 64) ch += cls[d] * head_w[d];
  ch = wave_sum(ch) + head_b[0];
  for (int b2 = 0; b2 < Bz; ++b2) {
    float a2 = 0.f;
    for (int e2 = lane; e2 < EDz; e2 += 64)
      a2 += ybuf[(size_t)b2 * EDz + e2] + ybuf[(size_t)(Bz + b2) * EDz + e2];
    a2 = wave_sum(a2);
    if (lane == 0) out[b2] = 1.f / (1.f + __expf(-(a2 + ch)));
  }
}

extern "C" void kernel_launch(void* const* d_in, const int* in_sizes, int n_in,
                              void* d_out, int out_size, void* d_ws, size_t ws_size,
                              hipStream_t stream) {
  const float* input_ids = (const float*)d_in[0];
  const int* n_tweets = (const int*)d_in[1];
  const int* n_words = (const int*)d_in[2];
  const float* cls = (const float*)d_in[3];
  const float* w_attn = (const float*)d_in[4];
  const float* b_attn = (const float*)d_in[5];
  const float* norm_w = (const float*)d_in[6];
  const float* ip[2] = {(const float*)d_in[7], (const float*)d_in[15]};
  const float* cw[2] = {(const float*)d_in[8], (const float*)d_in[16]};
  const float* cb[2] = {(const float*)d_in[9], (const float*)d_in[17]};
  const float* xpj[2] = {(const float*)d_in[10], (const float*)d_in[18]};
  const float* dtw[2] = {(const float*)d_in[11], (const float*)d_in[19]};
  const float* dtbp[2] = {(const float*)d_in[12], (const float*)d_in[20]};
  const float* Alog[2] = {(const float*)d_in[13], (const float*)d_in[21]};
  const float* Dpp[2] = {(const float*)d_in[14], (const float*)d_in[22]};
  const float* out_proj = (const float*)d_in[23];
  const float* head_w = (const float*)d_in[24];
  const float* head_b = (const float*)d_in[25];
  float* out = (float*)d_out;

  float* ws = (float*)d_ws;
  float* xn = ws;                           // 800800
  float* Pbuf = xn + 800800;                // 1638400
  float* xp_t = Pbuf + 1638400;             // 1638400
  float* dt_t = xp_t + 1638400;             // 1638400
  float* Bm_t = dt_t + 1638400;             // 65536
  float* dbcp = Bm_t + 65536;               // 1843200
  float* Cend = dbcp + 1843200;             // 128
  float* zbuf = Cend + 128;                 // 3200
  float* vbuf = zbuf + 3200;                // 400
  float* ybuf = vbuf + 400;                 // 3200
  int* cnts = (int*)(ybuf + 3200 + 64);     // 72 ints (64 mid + 1 scan)

  hipLaunchKernelGGL(k_front, dim3(9 + Bz * Tz / 4), dim3(256), 0, stream,
                     input_ids, n_tweets, n_words, w_attn, b_attn, norm_w,
                     cls, out_proj, head_w, ip[0], ip[1], xn, zbuf, vbuf, cnts);
  hipLaunchKernelGGL(k_gemm, dim3(2 * Bz * 8 * 7), dim3(256), 0, stream,
                     xn, ip[0], ip[1], Pbuf);
  hipLaunchKernelGGL(k_mid2, dim3(2 * Bz * 8 * ESP), dim3(256), 0, stream,
                     Pbuf, cw[0], cw[1], cb[0], cb[1], xpj[0], xpj[1],
                     dtw[0], dtw[1], dtbp[0], dtbp[1],
                     xp_t, dbcp, dt_t, Bm_t, Cend, cnts);
  hipLaunchKernelGGL(k_scan2, dim3(2 * Bz * EDz), dim3(64), 0, stream,
                     xp_t, dt_t, Bm_t, Cend, Alog[0], Alog[1], Dpp[0], Dpp[1],
                     zbuf, vbuf, ybuf, cls, head_w, head_b, out, cnts + 64);
}

// Round 10
// 97.655 us; speedup vs baseline: 3.8383x; 3.8383x over previous
//
#include <hip/hip_runtime.h>
#include <cmath>

#define Bz 4
#define Tz 1000
#define Wz 32
#define Dz 200
#define EDz 400
#define Nz 16
#define DTRz 13
#define Lz 1001
#define POSz 500
#define LPz 501
#define TSTR 512
#define NEE 7        // e-tiles of 64 in k_gemmid
#define NEG_BIG -1e30f

__device__ __forceinline__ float wave_sum(float v) {
#pragma unroll
  for (int o = 32; o; o >>= 1) v += __shfl_xor(v, o);
  return v;
}

// grid = 9 + 1000 blocks. blocks 0..8: setup. blocks 9..: pool (1 wave/tweet).
__global__ __launch_bounds__(256) void k_front(
    const float* __restrict__ x, const int* __restrict__ n_tweets,
    const int* __restrict__ n_words, const float* __restrict__ w_attn,
    const float* __restrict__ b_attn, const float* __restrict__ norm_w,
    const float* __restrict__ cls, const float* __restrict__ out_proj,
    const float* __restrict__ head_w, const float* __restrict__ ipf,
    const float* __restrict__ ipb, float* __restrict__ xn,
    float* __restrict__ zbuf, float* __restrict__ vbuf) {
  int bid = blockIdx.x;
  int tid = threadIdx.x;
  int wave = tid >> 6, lane = tid & 63;
  if (bid < 9) {
    if (bid == 0) {
      __shared__ float hw[Dz];
      if (tid < Dz) hw[tid] = head_w[tid];
      __syncthreads();
      for (int e = tid; e < EDz; e += 256) {
        float acc = 0.f;
        for (int d = 0; d < Dz; d += 4) {
          float4 ov = *(const float4*)(out_proj + e * Dz + d);
          acc += ov.x * hw[d] + ov.y * hw[d + 1] + ov.z * hw[d + 2] + ov.w * hw[d + 3];
        }
        vbuf[e] = acc;
      }
      return;
    }
    int id = bid - 1;
    int br = id >> 2, b = id & 3;
    __shared__ float xs[Dz];
    __shared__ float s_red[4];
    float val = (tid < Dz) ? cls[tid] : 0.f;
    float sq = wave_sum(val * val);
    if ((tid & 63) == 0) s_red[tid >> 6] = sq;
    __syncthreads();
    float tot = s_red[0] + s_red[1] + s_red[2] + s_red[3];
    float scale = rsqrtf(tot * (1.f / Dz) + 1e-5f);
    if (tid < Dz) {
      float o = val * scale * norm_w[tid];
      xs[tid] = o;
      if (br == 0) xn[((size_t)b * Lz + POSz) * Dz + tid] = o;
    }
    __syncthreads();
    const float* ip = br ? ipb : ipf;
    for (int e = tid; e < EDz; e += 256) {
      float acc = 0.f;
      for (int d = 0; d < Dz; ++d) acc += xs[d] * ip[d * (2 * EDz) + EDz + e];
      zbuf[((size_t)br * Bz + b) * EDz + e] = acc;
    }
    return;
  }
  int bt = (bid - 9) * 4 + wave;
  int b = bt / Tz, t = bt - b * Tz;
  int l = (t < POSz) ? t : t + 1;
  float* outr = xn + ((size_t)b * Lz + l) * Dz;
  int ntw = n_tweets[b]; if (ntw > Tz) ntw = Tz;
  if (t >= ntw) {
    if (lane < 50) *(float4*)(outr + lane * 4) = make_float4(0.f, 0.f, 0.f, 0.f);
    return;
  }
  int nw = n_words[b * Tz + t]; if (nw > Wz) nw = Wz; if (nw < 1) nw = 1;
  const float* xs = x + ((size_t)(b * Tz + t)) * (Wz * Dz);
  int h = lane & 1, w = lane >> 1;
  float sc = 0.f;
  if (w < nw) {
    const float* xr = xs + w * Dz + h * 100;
    const float* wr = w_attn + h * 100;
#pragma unroll
    for (int i = 0; i < 25; ++i) {
      float4 xv = *(const float4*)(xr + i * 4);
      float4 wv = *(const float4*)(wr + i * 4);
      sc += xv.x * wv.x + xv.y * wv.y + xv.z * wv.z + xv.w * wv.w;
    }
  }
  sc += __shfl_xor(sc, 1);
  float scv = (w < nw) ? (sc + b_attn[0]) : NEG_BIG;
  float m = scv;
#pragma unroll
  for (int o = 32; o; o >>= 1) m = fmaxf(m, __shfl_xor(m, o));
  float en = __expf(scv - m);
  float es = (h == 0) ? en : 0.f;
  float tot = wave_sum(es);
  en /= tot;
  float4 val = make_float4(0.f, 0.f, 0.f, 0.f);
  const float* xc = xs + lane * 4;
  for (int ww = 0; ww < nw; ++ww) {
    float aw = __shfl(en, 2 * ww);
    if (lane < 50) {
      float4 xv = *(const float4*)(xc + ww * Dz);
      val.x += aw * xv.x; val.y += aw * xv.y;
      val.z += aw * xv.z; val.w += aw * xv.w;
    }
  }
  float sq = (lane < 50) ? (val.x * val.x + val.y * val.y + val.z * val.z + val.w * val.w) : 0.f;
  sq = wave_sum(sq);
  float scale = rsqrtf(sq * (1.f / Dz) + 1e-5f);
  if (lane < 50) {
    float4 nw4 = *(const float4*)(norm_w + lane * 4);
    float4 o = make_float4(val.x * scale * nw4.x, val.y * scale * nw4.y,
                           val.z * scale * nw4.z, val.w * scale * nw4.w);
    *(float4*)(outr + lane * 4) = o;
  }
}

// Fused in_proj GEMM (80t incl. 8-row halo x 64e, P stays in LDS) -> causal
// conv+silu -> xp_t ; xproj partials -> dbcp[ee][brb][45][t].
// grid = brb(8) x tt(8) x ee(7) = 448 blocks, 256 threads.
__global__ __launch_bounds__(256) void k_gemmid(
    const float* __restrict__ xn,
    const float* __restrict__ ipf, const float* __restrict__ ipb,
    const float* __restrict__ cwf, const float* __restrict__ cwb,
    const float* __restrict__ cbf, const float* __restrict__ cbb,
    const float* __restrict__ xpjf, const float* __restrict__ xpjb,
    float* __restrict__ xp_t, float* __restrict__ dbcp) {
  int bid = blockIdx.x;
  int ee = bid % NEE;
  int rem = bid / NEE;
  int tt = rem & 7, brb = rem >> 3;
  int br = brb >> 2, b = brb & 3;
  int t0 = tt * 64, e0 = ee * 64;
  int tid = threadIdx.x;
  int wave = tid >> 6, lane = tid & 63;
  const float* ip = br ? ipb : ipf;
  const float* cw = br ? cwb : cwf;
  const float* cb = br ? cbb : cbf;
  const float* xpj = br ? xpjb : xpjf;

  __shared__ float Xs[16][85];       // [d][t(80)+pad]
  __shared__ float Ws[16][68];       // [d][e(64)+pad]
  __shared__ float Pl[80][69];       // [trow][e], trow = t - (t0-8)
  __shared__ float sred[4][64][45];

  int tx = tid & 15, ty = tid >> 4;  // tx: e-micro, ty: t-micro (5 rows each)
  float acc[5][4];
#pragma unroll
  for (int i = 0; i < 5; ++i)
#pragma unroll
    for (int j = 0; j < 4; ++j) acc[i][j] = 0.f;

  for (int dk = 0; dk < 200; dk += 16) {
    // stage X: 80 rows x 16 d
    float xv[5];
#pragma unroll
    for (int r = 0; r < 5; ++r) {
      int trow = r * 16 + ty;
      int t = t0 - 8 + trow;
      int d = dk + tx;
      float v = 0.f;
      if (t >= 0 && t < LPz && d < Dz) {
        int l = br ? (Lz - 1 - t) : t;
        v = xn[((size_t)b * Lz + l) * Dz + d];
      }
      xv[r] = v;
    }
    // stage W: 16 d x 64 e
    int dw = dk + ty;
    int e4 = e0 + tx * 4;
    float wv[4];
#pragma unroll
    for (int c = 0; c < 4; ++c) {
      int e = e4 + c;
      wv[c] = (dw < Dz && e < EDz) ? ip[(size_t)dw * (2 * EDz) + e] : 0.f;
    }
    __syncthreads();
#pragma unroll
    for (int r = 0; r < 5; ++r) Xs[tx][r * 16 + ty] = xv[r];
#pragma unroll
    for (int c = 0; c < 4; ++c) Ws[ty][tx * 4 + c] = wv[c];
    __syncthreads();
#pragma unroll
    for (int k = 0; k < 16; ++k) {
      float av[5], bv[4];
#pragma unroll
      for (int i = 0; i < 5; ++i) av[i] = Xs[k][ty * 5 + i];
#pragma unroll
      for (int j = 0; j < 4; ++j) bv[j] = Ws[k][tx * 4 + j];
#pragma unroll
      for (int i = 0; i < 5; ++i)
#pragma unroll
        for (int j = 0; j < 4; ++j) acc[i][j] += av[i] * bv[j];
    }
  }
  __syncthreads();
  // write P tile to LDS (scalar stores, stride-69 rows)
#pragma unroll
  for (int i = 0; i < 5; ++i)
#pragma unroll
    for (int j = 0; j < 4; ++j) Pl[ty * 5 + i][tx * 4 + j] = acc[i][j];
  __syncthreads();

  // conv + silu + xproj partials. wave w owns 16 e's; lane = t.
  float accq[45];
#pragma unroll
  for (int q = 0; q < 45; ++q) accq[q] = 0.f;
  int t = t0 + lane;
#pragma unroll 2
  for (int i = 0; i < 16; ++i) {
    int e_loc = wave * 16 + i;
    int e = e0 + e_loc;
    if (e < EDz) {
      int row = lane + 8;
      // P rows for t<0 are zero by construction (X masked) -> causal pad free
      float p0 = Pl[row - 3][e_loc];
      float p1 = Pl[row - 2][e_loc];
      float p2 = Pl[row - 1][e_loc];
      float p3 = Pl[row][e_loc];
      float4 c4 = *(const float4*)(cw + e * 4);
      float a = cb[e] + c4.x * p0 + c4.y * p1 + c4.z * p2 + c4.w * p3;
      float sp = a / (1.f + __expf(-a));
      xp_t[((size_t)brb * EDz + e) * TSTR + t] = sp;
      const float* xq = xpj + e * 45;
#pragma unroll
      for (int q = 0; q < 45; ++q) accq[q] += sp * xq[q];
    }
  }
#pragma unroll
  for (int q = 0; q < 45; ++q) sred[wave][lane][q] = accq[q];
  __syncthreads();
  if (wave < 2) {
#pragma unroll
    for (int q = 0; q < 45; ++q)
      sred[wave][lane][q] += sred[wave + 2][lane][q];
  }
  __syncthreads();
  if (wave == 0) {
    float* dp = dbcp + ((size_t)(ee * 8 + brb) * 45) * TSTR + t;
#pragma unroll
    for (int q = 0; q < 45; ++q)
      dp[(size_t)q * TSTR] = sred[0][lane][q] + sred[1][lane][q];
  }
}

// Sum NEE partials -> dfin[brb][13][t] + Bm_t + Cend. No dt here.
// grid = brb(8) x tc(8) x rg(4) = 256 blocks.
__global__ __launch_bounds__(256) void k_dt3(
    const float* __restrict__ dbcp, float* __restrict__ dfin_g,
    float* __restrict__ Bm_t, float* __restrict__ Cend) {
  int bid = blockIdx.x;
  int rg = bid & 3;
  int rem = bid >> 2;
  int tc = rem & 7, brb = rem >> 3;
  int tid = threadIdx.x;
  const size_t espstr = (size_t)8 * 45 * TSTR;
  int r0 = rg * 8;
  int nrows = (rg == 3) ? 5 : 8;         // rows 0..28 of dbcp (13 dfin + 16 Bm)
  for (int idx = tid; idx < nrows * 64; idx += 256) {
    int rl = idx >> 6, tl = idx & 63;
    int row = r0 + rl;
    size_t base = ((size_t)brb * 45 + row) * TSTR + tc * 64 + tl;
    float s = 0.f;
#pragma unroll
    for (int p = 0; p < NEE; ++p) s += dbcp[base + p * espstr];
    int tg = tc * 64 + tl;
    if (row < DTRz) dfin_g[((size_t)brb * DTRz + row) * TSTR + tg] = s;
    else Bm_t[((size_t)brb * Nz + (row - DTRz)) * TSTR + tg] = s;
  }
  if (rg == 3 && tc == 7 && tid < Nz) {
    size_t base = ((size_t)brb * 45 + 29 + tid) * TSTR + POSz;
    float s = 0.f;
#pragma unroll
    for (int p = 0; p < NEE; ++p) s += dbcp[base + p * espstr];
    Cend[brb * Nz + tid] = s;
  }
}

// Scan with on-the-fly dt = softplus(dtb[e] + sum_q dfin[q][t]*dtw[q][e]).
__global__ __launch_bounds__(64) void k_scan3(
    const float* __restrict__ xp_t, const float* __restrict__ dfin_g,
    const float* __restrict__ Bm_t, const float* __restrict__ Cend,
    const float* __restrict__ Alogf, const float* __restrict__ Alogb,
    const float* __restrict__ Dpf, const float* __restrict__ Dpb,
    const float* __restrict__ dtwf, const float* __restrict__ dtwb,
    const float* __restrict__ dtbf, const float* __restrict__ dtbb,
    const float* __restrict__ zbuf, const float* __restrict__ vbuf,
    float* __restrict__ ybuf) {
  int blk = blockIdx.x;
  int br = blk / (Bz * EDz);
  int rem = blk - br * (Bz * EDz);
  int b = rem / EDz, e = rem - b * EDz;
  int brb = br * Bz + b;
  int lane = threadIdx.x;
  const float* A_log = br ? Alogb : Alogf;
  const float* Dp = br ? Dpb : Dpf;
  const float* dtw = br ? dtwb : dtwf;
  const float* dtb = br ? dtbb : dtbf;
  float A[Nz];
  {
    const float4* ap = (const float4*)(A_log + e * Nz);
#pragma unroll
    for (int q = 0; q < 4; ++q) {
      float4 a4 = ap[q];
      A[q * 4 + 0] = -__expf(a4.x); A[q * 4 + 1] = -__expf(a4.y);
      A[q * 4 + 2] = -__expf(a4.z); A[q * 4 + 3] = -__expf(a4.w);
    }
  }
  float wq[DTRz];
#pragma unroll
  for (int q = 0; q < DTRz; ++q) wq[q] = dtw[q * EDz + e];
  float dtbe = dtb[e];
  const float* dfb = dfin_g + (size_t)brb * DTRz * TSTR;
  const float* xpp = xp_t + ((size_t)brb * EDz + e) * TSTR;
  const float* bmp = Bm_t + (size_t)brb * Nz * TSTR;

  // pass A: dt per chunk (kept in regs) + total
  float dtt_r[8];
  float loc = 0.f;
#pragma unroll
  for (int c = 0; c < 8; ++c) {
    int t = c * 64 + lane;
    float s = dtbe;
#pragma unroll
    for (int q = 0; q < DTRz; ++q) s += dfb[(size_t)q * TSTR + t] * wq[q];
    float dtv = (s > 20.f) ? s : log1pf(__expf(s));
    dtv = (t < LPz) ? dtv : 0.f;
    dtt_r[c] = dtv;
    loc += dtv;
  }
  float Stot = wave_sum(loc);
  float acc[Nz];
#pragma unroll
  for (int n = 0; n < Nz; ++n) acc[n] = 0.f;
  float carry = 0.f;
  for (int c = 0; c < 8; ++c) {
    int t = c * 64 + lane;
    bool act = t < LPz;
    float dtt = dtt_r[c];
    float xv = act ? xpp[t] : 0.f;
    float s = dtt;
#pragma unroll
    for (int o = 1; o < 64; o <<= 1) {
      float u = __shfl_up(s, o);
      s += (lane >= o) ? u : 0.f;
    }
    float S = carry + s;
    carry += __shfl(s, 63);
    float wt = dtt * xv;
    float decay = Stot - S;  // >= 0, A<0 => exp<=1
#pragma unroll
    for (int n = 0; n < Nz; ++n) {
      float bv = act ? bmp[n * TSTR + t] : 0.f;
      acc[n] += __expf(A[n] * decay) * wt * bv;
    }
  }
#pragma unroll
  for (int o = 32; o; o >>= 1) {
#pragma unroll
    for (int n = 0; n < Nz; ++n) acc[n] += __shfl_xor(acc[n], o);
  }
  if (lane == 0) {
    float y = Dp[e] * xpp[LPz - 1];
#pragma unroll
    for (int n = 0; n < Nz; ++n) y += Cend[brb * Nz + n] * acc[n];
    float zz = zbuf[(size_t)brb * EDz + e];
    float sz = zz / (1.f + __expf(-zz));
    ybuf[(size_t)brb * EDz + e] = y * sz * vbuf[e];
  }
}

__global__ __launch_bounds__(256) void k_final(
    const float* __restrict__ cls, const float* __restrict__ head_w,
    const float* __restrict__ head_b, const float* __restrict__ ybuf,
    float* __restrict__ out) {
  int tid = threadIdx.x;
  int b = tid >> 6, lane = tid & 63;
  float acc = 0.f;
  for (int e = lane; e < EDz; e += 64)
    acc += ybuf[(size_t)b * EDz + e] + ybuf[(size_t)(Bz + b) * EDz + e];
  for (int d = lane; d < Dz; d += 64) acc += cls[d] * head_w[d];
  acc = wave_sum(acc);
  if (lane == 0) out[b] = 1.f / (1.f + __expf(-(acc + head_b[0])));
}

extern "C" void kernel_launch(void* const* d_in, const int* in_sizes, int n_in,
                              void* d_out, int out_size, void* d_ws, size_t ws_size,
                              hipStream_t stream) {
  const float* input_ids = (const float*)d_in[0];
  const int* n_tweets = (const int*)d_in[1];
  const int* n_words = (const int*)d_in[2];
  const float* cls = (const float*)d_in[3];
  const float* w_attn = (const float*)d_in[4];
  const float* b_attn = (const float*)d_in[5];
  const float* norm_w = (const float*)d_in[6];
  const float* ip[2] = {(const float*)d_in[7], (const float*)d_in[15]};
  const float* cw[2] = {(const float*)d_in[8], (const float*)d_in[16]};
  const float* cb[2] = {(const float*)d_in[9], (const float*)d_in[17]};
  const float* xpj[2] = {(const float*)d_in[10], (const float*)d_in[18]};
  const float* dtw[2] = {(const float*)d_in[11], (const float*)d_in[19]};
  const float* dtbp[2] = {(const float*)d_in[12], (const float*)d_in[20]};
  const float* Alog[2] = {(const float*)d_in[13], (const float*)d_in[21]};
  const float* Dpp[2] = {(const float*)d_in[14], (const float*)d_in[22]};
  const float* out_proj = (const float*)d_in[23];
  const float* head_w = (const float*)d_in[24];
  const float* head_b = (const float*)d_in[25];
  float* out = (float*)d_out;

  float* ws = (float*)d_ws;
  float* xn = ws;                           // 800800
  float* xp_t = xn + 800800;                // 2*4*400*512 = 1638400
  float* Bm_t = xp_t + 1638400;             // 65536
  float* dbcp = Bm_t + 65536;               // 7*8*45*512 = 1290240
  float* dfin = dbcp + 1290240;             // 8*13*512 = 53248
  float* Cend = dfin + 53248;               // 128
  float* zbuf = Cend + 128;                 // 3200
  float* vbuf = zbuf + 3200;                // 400
  float* ybuf = vbuf + 400;                 // 3200
  // total ~3.86M floats ~15.4 MB

  hipLaunchKernelGGL(k_front, dim3(9 + Bz * Tz / 4), dim3(256), 0, stream,
                     input_ids, n_tweets, n_words, w_attn, b_attn, norm_w,
                     cls, out_proj, head_w, ip[0], ip[1], xn, zbuf, vbuf);
  hipLaunchKernelGGL(k_gemmid, dim3(2 * Bz * 8 * NEE), dim3(256), 0, stream,
                     xn, ip[0], ip[1], cw[0], cw[1], cb[0], cb[1],
                     xpj[0], xpj[1], xp_t, dbcp);
  hipLaunchKernelGGL(k_dt3, dim3(2 * Bz * 8 * 4), dim3(256), 0, stream,
                     dbcp, dfin, Bm_t, Cend);
  hipLaunchKernelGGL(k_scan3, dim3(2 * Bz * EDz), dim3(64), 0, stream,
                     xp_t, dfin, Bm_t, Cend, Alog[0], Alog[1], Dpp[0], Dpp[1],
                     dtw[0], dtw[1], dtbp[0], dtbp[1], zbuf, vbuf, ybuf);
  hipLaunchKernelGGL(k_final, dim3(1), dim3(256), 0, stream,
                     cls, head_w, head_b, ybuf, out);
}